// Round 2
// baseline (486.756 us; speedup 1.0000x reference)
//
#include <hip/hip_runtime.h>
#include <hip/hip_bf16.h>
#include <stdint.h>

typedef unsigned short u16;
typedef unsigned int   u32;

#define BATCH  64
#define NXS    512
#define NYS    512
#define NHEAD  8
#define DHEAD  10
#define DMODEL 80     // NHEAD*DHEAD
#define DXK    768    // x feature dim
#define DYK    283    // y feature dim

typedef __attribute__((ext_vector_type(8))) short short8;
typedef __attribute__((ext_vector_type(4))) float floatx4;

// ---------- bf16 helpers (bit-level, RNE) ----------
__device__ inline u16 f2b(float f) {
  u32 x = __builtin_bit_cast(u32, f);
  u32 r = (x + 0x7fffu + ((x >> 16) & 1u)) >> 16;
  return (u16)r;
}
__device__ inline float b2f_lo(u32 u) { return __builtin_bit_cast(float, u << 16); }
__device__ inline float b2f_hi(u32 u) { return __builtin_bit_cast(float, u & 0xffff0000u); }

// =====================================================================
// Q projection: Qw(32768,80)bf16 = X(32768,768)fp32 @ Wq(768,80)fp32
// block: 256 thr (4 waves), tile M=64 (16 rows/wave), N=80 (5x16), K-step 32
// MFMA layouts (verified gfx950): A[m=lane&15][k=quad*8+j],
// B[k=quad*8+j][n=lane&15] (stored col-major in LDS), D row=quad*4+p, col=lane&15
// =====================================================================
__global__ __launch_bounds__(256) void proj_q(const float* __restrict__ X,
                                              const float* __restrict__ W,
                                              u16* __restrict__ O) {
  __shared__ u16 Xs[64 * 40];   // row stride 40 bf16 (80B)
  __shared__ u16 Ws[80 * 40];   // W transposed: Ws[c][kk]
  const int t = threadIdx.x;
  const int wv = t >> 6, lane = t & 63;
  const int m16 = lane & 15, quad = lane >> 4;
  const int row0 = blockIdx.x * 64;

  floatx4 acc[5];
#pragma unroll
  for (int i = 0; i < 5; ++i) acc[i] = (floatx4){0.f, 0.f, 0.f, 0.f};

  for (int k0 = 0; k0 < DXK; k0 += 32) {
    // stage X tile: 64 rows x 32 k fp32 -> bf16. 512 float4, 2 per thread
#pragma unroll
    for (int it = 0; it < 2; ++it) {
      const int f = t + 256 * it;
      const int r = f >> 3, kk = (f & 7) << 2;
      const float4 v = *reinterpret_cast<const float4*>(&X[(size_t)(row0 + r) * DXK + k0 + kk]);
      ushort4 bv;
      bv.x = f2b(v.x); bv.y = f2b(v.y); bv.z = f2b(v.z); bv.w = f2b(v.w);
      *reinterpret_cast<ushort4*>(&Xs[r * 40 + kk]) = bv;
    }
    // stage W chunk transposed: 32 k x 80 c (scalar fp32 loads)
    for (int idx = t; idx < 32 * 80; idx += 256) {
      const int kk = idx / 80;
      const int c = idx - kk * 80;
      Ws[c * 40 + kk] = f2b(W[(size_t)(k0 + kk) * 80 + c]);
    }
    __syncthreads();
    const short8 a = *reinterpret_cast<const short8*>(&Xs[(wv * 16 + m16) * 40 + quad * 8]);
#pragma unroll
    for (int nt = 0; nt < 5; ++nt) {
      const short8 b = *reinterpret_cast<const short8*>(&Ws[(nt * 16 + m16) * 40 + quad * 8]);
      acc[nt] = __builtin_amdgcn_mfma_f32_16x16x32_bf16(a, b, acc[nt], 0, 0, 0);
    }
    __syncthreads();
  }
#pragma unroll
  for (int nt = 0; nt < 5; ++nt) {
    const int col = nt * 16 + m16;
#pragma unroll
    for (int p = 0; p < 4; ++p) {
      const int grow = row0 + wv * 16 + quad * 4 + p;
      O[(size_t)grow * DMODEL + col] = f2b(acc[nt][p]);
    }
  }
}

// =====================================================================
// K/V projection (fused): Kw,Vw(32768,80)bf16 = Y(32768,283)fp32 @ {Wk,Wv}fp32
// outputs written in (b, h, ny, 10) bf16 layout for attention staging
// =====================================================================
__global__ __launch_bounds__(256) void proj_kv(const float* __restrict__ Y,
                                               const float* __restrict__ Wk,
                                               const float* __restrict__ Wv,
                                               u16* __restrict__ Ko,
                                               u16* __restrict__ Vo) {
  __shared__ u16 Ys[64 * 40];
  __shared__ u16 Wks[80 * 40];
  __shared__ u16 Wvs[80 * 40];
  const int t = threadIdx.x;
  const int wv = t >> 6, lane = t & 63;
  const int m16 = lane & 15, quad = lane >> 4;
  const int row0 = blockIdx.x * 64;

  floatx4 ak[5], av[5];
#pragma unroll
  for (int i = 0; i < 5; ++i) {
    ak[i] = (floatx4){0.f, 0.f, 0.f, 0.f};
    av[i] = (floatx4){0.f, 0.f, 0.f, 0.f};
  }

  for (int k0 = 0; k0 < 288; k0 += 32) {  // 283 padded to 288
    for (int idx = t; idx < 2048; idx += 256) {  // Y tile (scalar, stride 283)
      const int r = idx >> 5, kk = idx & 31;
      const int k = k0 + kk;
      Ys[r * 40 + kk] = (k < DYK) ? f2b(Y[(size_t)(row0 + r) * DYK + k]) : (u16)0;
    }
    for (int idx = t; idx < 2560; idx += 256) {
      const int kk = idx / 80, c = idx - kk * 80;
      const int k = k0 + kk;
      u16 wk = 0, wvv = 0;
      if (k < DYK) {
        wk  = f2b(Wk[(size_t)k * 80 + c]);
        wvv = f2b(Wv[(size_t)k * 80 + c]);
      }
      Wks[c * 40 + kk] = wk;
      Wvs[c * 40 + kk] = wvv;
    }
    __syncthreads();
    const short8 a = *reinterpret_cast<const short8*>(&Ys[(wv * 16 + m16) * 40 + quad * 8]);
#pragma unroll
    for (int nt = 0; nt < 5; ++nt) {
      const short8 bk = *reinterpret_cast<const short8*>(&Wks[(nt * 16 + m16) * 40 + quad * 8]);
      ak[nt] = __builtin_amdgcn_mfma_f32_16x16x32_bf16(a, bk, ak[nt], 0, 0, 0);
      const short8 bv = *reinterpret_cast<const short8*>(&Wvs[(nt * 16 + m16) * 40 + quad * 8]);
      av[nt] = __builtin_amdgcn_mfma_f32_16x16x32_bf16(a, bv, av[nt], 0, 0, 0);
    }
    __syncthreads();
  }
#pragma unroll
  for (int nt = 0; nt < 5; ++nt) {
    const int col = nt * 16 + m16;
    const int h = col / 10, d = col - h * 10;
#pragma unroll
    for (int p = 0; p < 4; ++p) {
      const int grow = row0 + wv * 16 + quad * 4 + p;
      const int bb = grow >> 9;       // row = b*512 + ny
      const int ny = grow & 511;
      const size_t o = (((size_t)bb * NHEAD + h) * NYS + ny) * DHEAD + d;
      Ko[o] = f2b(ak[nt][p]);
      Vo[o] = f2b(av[nt][p]);
    }
  }
}

// =====================================================================
// Attention: one block per (b,h). 256 thr x 2 q-rows. K/V staged in LDS
// (bf16 as u32 pairs, 20 KB). No-max softmax (|s*scale| <~ 1.5, exp safe):
// l = sum exp(s), acc = sum exp(s)*v ; out = q + acc/l (residual), fp32 out.
// =====================================================================
__global__ __launch_bounds__(256) void attn(const u16* __restrict__ Q,
                                            const u16* __restrict__ K,
                                            const u16* __restrict__ V,
                                            float* __restrict__ O) {
  __shared__ u32 ks[NYS * 5];   // 512 keys x 10 bf16 = 5 u32 each
  __shared__ u32 vs[NYS * 5];
  const int t = threadIdx.x;
  const int b = blockIdx.x >> 3;
  const int h = blockIdx.x & 7;

  const u32* Kg = reinterpret_cast<const u32*>(K) + (size_t)(b * NHEAD + h) * NYS * 5;
  const u32* Vg = reinterpret_cast<const u32*>(V) + (size_t)(b * NHEAD + h) * NYS * 5;
  for (int idx = t; idx < NYS * 5 / 4; idx += 256) {  // 640 uint4 each
    reinterpret_cast<uint4*>(ks)[idx] = reinterpret_cast<const uint4*>(Kg)[idx];
    reinterpret_cast<uint4*>(vs)[idx] = reinterpret_cast<const uint4*>(Vg)[idx];
  }
  __syncthreads();

  float q[2][10], accv[2][10], l[2];
#pragma unroll
  for (int i = 0; i < 2; ++i) {
    l[i] = 0.f;
    const u32* Qg = reinterpret_cast<const u32*>(Q) +
                    ((size_t)b * NXS + t + 256 * i) * 40 + h * 5;
#pragma unroll
    for (int dd = 0; dd < 5; ++dd) {
      const u32 u = Qg[dd];
      q[i][2 * dd]     = b2f_lo(u);
      q[i][2 * dd + 1] = b2f_hi(u);
      accv[i][2 * dd]     = 0.f;
      accv[i][2 * dd + 1] = 0.f;
    }
  }

  const float scale = 0.31622776601683794f;  // 1/sqrt(10)
  for (int j = 0; j < NYS; ++j) {
    float kf[10];
#pragma unroll
    for (int dd = 0; dd < 5; ++dd) {
      const u32 u = ks[j * 5 + dd];  // wave-uniform addr -> LDS broadcast
      kf[2 * dd]     = b2f_lo(u);
      kf[2 * dd + 1] = b2f_hi(u);
    }
    float p[2];
#pragma unroll
    for (int i = 0; i < 2; ++i) {
      float s = 0.f;
#pragma unroll
      for (int d = 0; d < 10; ++d) s = fmaf(q[i][d], kf[d], s);
      p[i] = __expf(s * scale);
      l[i] += p[i];
    }
    float vf[10];
#pragma unroll
    for (int dd = 0; dd < 5; ++dd) {
      const u32 u = vs[j * 5 + dd];
      vf[2 * dd]     = b2f_lo(u);
      vf[2 * dd + 1] = b2f_hi(u);
    }
#pragma unroll
    for (int i = 0; i < 2; ++i) {
#pragma unroll
      for (int d = 0; d < 10; ++d) accv[i][d] = fmaf(p[i], vf[d], accv[i][d]);
    }
  }

#pragma unroll
  for (int i = 0; i < 2; ++i) {
    const int r = t + 256 * i;
    const float inv = 1.f / l[i];
    float* Og = O + ((size_t)b * NXS + r) * DMODEL + h * DHEAD;
#pragma unroll
    for (int dd = 0; dd < 5; ++dd) {   // 5 x float2 (8B-aligned)
      float2 o2;
      o2.x = q[i][2 * dd]     + accv[i][2 * dd] * inv;
      o2.y = q[i][2 * dd + 1] + accv[i][2 * dd + 1] * inv;
      *reinterpret_cast<float2*>(Og + 2 * dd) = o2;
    }
  }
}

extern "C" void kernel_launch(void* const* d_in, const int* in_sizes, int n_in,
                              void* d_out, int out_size, void* d_ws, size_t ws_size,
                              hipStream_t stream) {
  const float* x  = (const float*)d_in[0];   // (64,512,768) fp32
  const float* y  = (const float*)d_in[1];   // (64,512,283) fp32
  const float* Wq = (const float*)d_in[2];   // (768,80) fp32
  const float* Wk = (const float*)d_in[3];   // (283,80) fp32
  const float* Wv = (const float*)d_in[4];   // (283,80) fp32
  float* out = (float*)d_out;                // (64, 512*80) fp32

  // compact bf16 workspace: Q 5.25MB | K 5.25MB | V 5.25MB = 15.75MB total
  char* ws = (char*)d_ws;
  u16* Qw = (u16*)(ws);
  u16* Kw = (u16*)(ws + 5242880);
  u16* Vw = (u16*)(ws + 10485760);

  proj_q <<<512, 256, 0, stream>>>(x, Wq, Qw);
  proj_kv<<<512, 256, 0, stream>>>(y, Wk, Wv, Kw, Vw);
  attn   <<<512, 256, 0, stream>>>(Qw, Kw, Vw, out);
}

// Round 3
// 238.319 us; speedup vs baseline: 2.0425x; 2.0425x over previous
//
#include <hip/hip_runtime.h>
#include <stdint.h>

typedef unsigned short u16;
typedef unsigned int   u32;
typedef _Float16       f16;

typedef __attribute__((ext_vector_type(2))) _Float16 half2v;
typedef __attribute__((ext_vector_type(4))) _Float16 half4v;
typedef __attribute__((ext_vector_type(8))) _Float16 half8v;
typedef __attribute__((ext_vector_type(4))) float    floatx4;

#define NXS    512
#define NYS    512
#define NHEAD  8
#define DHEAD  10
#define DMODEL 80
#define DXK    768
#define DYK    283

__device__ inline half2v pk2(float x, float y) {
  return __builtin_bit_cast(half2v, __builtin_amdgcn_cvt_pkrtz(x, y));
}
__device__ inline half4v cvt4(float4 v) {
  return __builtin_shufflevector(pk2(v.x, v.y), pk2(v.z, v.w), 0, 1, 2, 3);
}

// =====================================================================
// w_prep: transpose + fp32->f16 the three weight matrices.
// Tq[c][k] (80x768), Tk/Tv[c][k] (80x288, k zero-padded past 283)
// =====================================================================
__global__ __launch_bounds__(256) void w_prep(const float* __restrict__ Wq,
                                              const float* __restrict__ Wk,
                                              const float* __restrict__ Wv,
                                              f16* __restrict__ Tq,
                                              f16* __restrict__ Tk,
                                              f16* __restrict__ Tv) {
  const int idx = blockIdx.x * 256 + threadIdx.x;
  if (idx < 80 * 768) {
    const int c = idx / 768, k = idx - c * 768;
    Tq[idx] = (f16)Wq[k * 80 + c];
  }
  if (idx < 80 * 288) {
    const int c = idx / 288, k = idx - c * 288;
    float a = 0.f, b = 0.f;
    if (k < DYK) { a = Wk[k * 80 + c]; b = Wv[k * 80 + c]; }
    Tk[idx] = (f16)a;
    Tv[idx] = (f16)b;
  }
}

// =====================================================================
// proj_q: Qw(32768,80)f16 = X(32768,768)fp32 @ Wq. Software-pipelined:
// prefetch next K-slice to regs while MFMA consumes LDS. M-tile 64, K-step 32.
// =====================================================================
__global__ __launch_bounds__(256) void proj_q(const float* __restrict__ X,
                                              const f16* __restrict__ Wt,
                                              f16* __restrict__ O) {
  __shared__ f16 Xs[64 * 40];
  __shared__ f16 Ws[80 * 40];
  const int t = threadIdx.x;
  const int wv = t >> 6, lane = t & 63, m16 = lane & 15, quad = lane >> 4;
  const int row0 = blockIdx.x * 64;
  const int xr_r = t >> 3, xr_k = (t & 7) << 2;   // second load: row +32, same k
  const int wi0 = t, wi1 = t + 160;

  float4 xr0, xr1;
  uint4 wr0, wr1;
  xr0 = *(const float4*)&X[(size_t)(row0 + xr_r) * DXK + xr_k];
  xr1 = *(const float4*)&X[(size_t)(row0 + xr_r + 32) * DXK + xr_k];
  if (t < 160) {
    wr0 = *(const uint4*)&Wt[(wi0 >> 2) * DXK + (wi0 & 3) * 8];
    wr1 = *(const uint4*)&Wt[(wi1 >> 2) * DXK + (wi1 & 3) * 8];
  }

  floatx4 acc[5];
#pragma unroll
  for (int i = 0; i < 5; ++i) acc[i] = (floatx4){0.f, 0.f, 0.f, 0.f};

  for (int s = 0; s < 24; ++s) {
    if (s) __syncthreads();
    *(half4v*)&Xs[xr_r * 40 + xr_k] = cvt4(xr0);
    *(half4v*)&Xs[(xr_r + 32) * 40 + xr_k] = cvt4(xr1);
    if (t < 160) {
      *(uint4*)&Ws[(wi0 >> 2) * 40 + (wi0 & 3) * 8] = wr0;
      *(uint4*)&Ws[(wi1 >> 2) * 40 + (wi1 & 3) * 8] = wr1;
    }
    __syncthreads();
    if (s < 23) {
      const int k0 = (s + 1) * 32;
      xr0 = *(const float4*)&X[(size_t)(row0 + xr_r) * DXK + k0 + xr_k];
      xr1 = *(const float4*)&X[(size_t)(row0 + xr_r + 32) * DXK + k0 + xr_k];
      if (t < 160) {
        wr0 = *(const uint4*)&Wt[(wi0 >> 2) * DXK + k0 + (wi0 & 3) * 8];
        wr1 = *(const uint4*)&Wt[(wi1 >> 2) * DXK + k0 + (wi1 & 3) * 8];
      }
    }
    const half8v a = *(const half8v*)&Xs[(wv * 16 + m16) * 40 + quad * 8];
#pragma unroll
    for (int nt = 0; nt < 5; ++nt) {
      const half8v b = *(const half8v*)&Ws[(nt * 16 + m16) * 40 + quad * 8];
      acc[nt] = __builtin_amdgcn_mfma_f32_16x16x32_f16(a, b, acc[nt], 0, 0, 0);
    }
  }
#pragma unroll
  for (int nt = 0; nt < 5; ++nt) {
    const int col = nt * 16 + m16;
#pragma unroll
    for (int p = 0; p < 4; ++p) {
      const int grow = row0 + wv * 16 + quad * 4 + p;
      O[(size_t)grow * DMODEL + col] = (f16)acc[nt][p];
    }
  }
}

// =====================================================================
// proj_kv: K,V = Y(32768,283)fp32 @ {Wk,Wv}; outputs f16 in (b,h,ny,10).
// Pipelined like proj_q; Y staged with scalar loads (stride 283 kills float4).
// =====================================================================
__global__ __launch_bounds__(256) void proj_kv(const float* __restrict__ Y,
                                               const f16* __restrict__ Wtk,
                                               const f16* __restrict__ Wtv,
                                               f16* __restrict__ Ko,
                                               f16* __restrict__ Vo) {
  __shared__ f16 Ys[64 * 40];
  __shared__ f16 Wks[80 * 40];
  __shared__ f16 Wvs[80 * 40];
  const int t = threadIdx.x;
  const int wv = t >> 6, lane = t & 63, m16 = lane & 15, quad = lane >> 4;
  const int row0 = blockIdx.x * 64;
  const int wi0 = t, wi1 = t + 160;

  float yr[8];
  uint4 wk0, wk1, wv0, wv1;
#pragma unroll
  for (int i = 0; i < 8; ++i) {
    const int idx = t + 256 * i;
    const int r = idx >> 5, kk = idx & 31;
    yr[i] = (kk < DYK) ? Y[(size_t)(row0 + r) * DYK + kk] : 0.f;
  }
  if (t < 160) {
    wk0 = *(const uint4*)&Wtk[(wi0 >> 2) * 288 + (wi0 & 3) * 8];
    wk1 = *(const uint4*)&Wtk[(wi1 >> 2) * 288 + (wi1 & 3) * 8];
    wv0 = *(const uint4*)&Wtv[(wi0 >> 2) * 288 + (wi0 & 3) * 8];
    wv1 = *(const uint4*)&Wtv[(wi1 >> 2) * 288 + (wi1 & 3) * 8];
  }

  floatx4 ak[5], av[5];
#pragma unroll
  for (int i = 0; i < 5; ++i) {
    ak[i] = (floatx4){0.f, 0.f, 0.f, 0.f};
    av[i] = (floatx4){0.f, 0.f, 0.f, 0.f};
  }

  for (int s = 0; s < 9; ++s) {   // 288/32
    if (s) __syncthreads();
#pragma unroll
    for (int i = 0; i < 8; ++i) {
      const int idx = t + 256 * i;
      Ys[(idx >> 5) * 40 + (idx & 31)] = (f16)yr[i];
    }
    if (t < 160) {
      *(uint4*)&Wks[(wi0 >> 2) * 40 + (wi0 & 3) * 8] = wk0;
      *(uint4*)&Wks[(wi1 >> 2) * 40 + (wi1 & 3) * 8] = wk1;
      *(uint4*)&Wvs[(wi0 >> 2) * 40 + (wi0 & 3) * 8] = wv0;
      *(uint4*)&Wvs[(wi1 >> 2) * 40 + (wi1 & 3) * 8] = wv1;
    }
    __syncthreads();
    if (s < 8) {
      const int k0 = (s + 1) * 32;
#pragma unroll
      for (int i = 0; i < 8; ++i) {
        const int idx = t + 256 * i;
        const int r = idx >> 5, k = k0 + (idx & 31);
        yr[i] = (k < DYK) ? Y[(size_t)(row0 + r) * DYK + k] : 0.f;
      }
      if (t < 160) {
        wk0 = *(const uint4*)&Wtk[(wi0 >> 2) * 288 + k0 + (wi0 & 3) * 8];
        wk1 = *(const uint4*)&Wtk[(wi1 >> 2) * 288 + k0 + (wi1 & 3) * 8];
        wv0 = *(const uint4*)&Wtv[(wi0 >> 2) * 288 + k0 + (wi0 & 3) * 8];
        wv1 = *(const uint4*)&Wtv[(wi1 >> 2) * 288 + k0 + (wi1 & 3) * 8];
      }
    }
    const half8v a = *(const half8v*)&Ys[(wv * 16 + m16) * 40 + quad * 8];
#pragma unroll
    for (int nt = 0; nt < 5; ++nt) {
      const half8v bk = *(const half8v*)&Wks[(nt * 16 + m16) * 40 + quad * 8];
      ak[nt] = __builtin_amdgcn_mfma_f32_16x16x32_f16(a, bk, ak[nt], 0, 0, 0);
      const half8v bv = *(const half8v*)&Wvs[(nt * 16 + m16) * 40 + quad * 8];
      av[nt] = __builtin_amdgcn_mfma_f32_16x16x32_f16(a, bv, av[nt], 0, 0, 0);
    }
  }
#pragma unroll
  for (int nt = 0; nt < 5; ++nt) {
    const int col = nt * 16 + m16;
    const int h = col / 10, d = col - h * 10;
#pragma unroll
    for (int p = 0; p < 4; ++p) {
      const int grow = row0 + wv * 16 + quad * 4 + p;
      const int bb = grow >> 9, ny = grow & 511;
      const size_t o = (((size_t)bb * NHEAD + h) * NYS + ny) * DHEAD + d;
      Ko[o] = (f16)ak[nt][p];
      Vo[o] = (f16)av[nt][p];
    }
  }
}

// =====================================================================
// attn: one block per (b,h), 4 waves, 8 q-tiles (16 rows) per wave.
// MFMA1: S^T = K·Q^T (16x16x16, d padded to 16) -> C/D layout (key=quad*4+p,
// q=lane&15) == A-operand layout of P for MFMA2: O = P·V. No-max softmax.
// LDS strides padded (20 / 520 f16) to keep bank conflicts <=2-way.
// =====================================================================
__global__ __launch_bounds__(256) void attn(const f16* __restrict__ Q,
                                            const f16* __restrict__ K,
                                            const f16* __restrict__ V,
                                            float* __restrict__ O) {
  __shared__ f16 Qs[512 * 20];   // [q][d], d padded 16->20
  __shared__ f16 Ks[512 * 20];   // [key][d]
  __shared__ f16 Vt[16 * 520];   // [d][key], key stride padded 512->520
  const int t = threadIdx.x;
  const int wv = t >> 6, lane = t & 63, m16 = lane & 15, quad = lane >> 4;
  const int b = blockIdx.x >> 3, h = blockIdx.x & 7;

  u32* Qs32 = (u32*)Qs;
  u32* Ks32 = (u32*)Ks;
  u32* Vt32 = (u32*)Vt;
  const u32* Qg = (const u32*)Q + (size_t)b * NXS * 40 + h * 5;   // row stride 40 u32
  const u32* Kg = (const u32*)K + (size_t)(b * NHEAD + h) * NYS * 5;
  const u32* Vg = (const u32*)V + (size_t)(b * NHEAD + h) * NYS * 5;

  for (int idx = t; idx < 2560; idx += 256) {
    const u32 row = (u32)idx / 5u, c = (u32)idx - row * 5u;
    Qs32[row * 10 + c] = Qg[row * 40 + c];
    Ks32[row * 10 + c] = Kg[idx];
    const half2v hv = __builtin_bit_cast(half2v, Vg[idx]);
    Vt[(2 * c) * 520 + row] = hv[0];
    Vt[(2 * c + 1) * 520 + row] = hv[1];
  }
  for (int idx = t; idx < 2560; idx += 256) {   // zero d-pad (d=10..19)
    const u32 row = (u32)idx / 5u, c = 5u + ((u32)idx - row * 5u);
    Qs32[row * 10 + c] = 0u;
    Ks32[row * 10 + c] = 0u;
  }
  for (int idx = t; idx < 1560; idx += 256) {   // zero Vt rows d=10..15
    Vt32[2600 + idx] = 0u;
  }
  __syncthreads();

  const float scale = 0.31622776601683794f;   // 1/sqrt(10)
#pragma unroll 1
  for (int i = 0; i < 8; ++i) {
    const int qt = wv * 8 + i;
    const half4v qf = *(const half4v*)&Qs[(qt * 16 + m16) * 20 + quad * 4];
    floatx4 oacc = (floatx4){0.f, 0.f, 0.f, 0.f};
    float lp = 0.f;
    for (int kt = 0; kt < 32; ++kt) {
      const half4v kf = *(const half4v*)&Ks[(kt * 16 + m16) * 20 + quad * 4];
      floatx4 s = __builtin_amdgcn_mfma_f32_16x16x16f16(kf, qf,
                    (floatx4){0.f, 0.f, 0.f, 0.f}, 0, 0, 0);
      const float p0 = __expf(s[0] * scale);
      const float p1 = __expf(s[1] * scale);
      const float p2 = __expf(s[2] * scale);
      const float p3 = __expf(s[3] * scale);
      lp += (p0 + p1) + (p2 + p3);
      const half4v pf = __builtin_shufflevector(pk2(p0, p1), pk2(p2, p3), 0, 1, 2, 3);
      const half4v vf = *(const half4v*)&Vt[m16 * 520 + kt * 16 + quad * 4];
      oacc = __builtin_amdgcn_mfma_f32_16x16x16f16(pf, vf, oacc, 0, 0, 0);
    }
    lp += __shfl_xor(lp, 16);
    lp += __shfl_xor(lp, 32);   // all lanes: l for q-row (qt*16 + m16)
#pragma unroll
    for (int p = 0; p < 4; ++p) {
      const int rq = qt * 16 + quad * 4 + p;
      const float lr = __shfl(lp, quad * 4 + p);
      const float qv = (float)Qs[rq * 20 + m16];
      const float val = qv + oacc[p] / lr;
      if (m16 < DHEAD)
        O[((size_t)b * NXS + rq) * DMODEL + h * DHEAD + m16] = val;
    }
  }
}

extern "C" void kernel_launch(void* const* d_in, const int* in_sizes, int n_in,
                              void* d_out, int out_size, void* d_ws, size_t ws_size,
                              hipStream_t stream) {
  const float* x  = (const float*)d_in[0];
  const float* y  = (const float*)d_in[1];
  const float* Wq = (const float*)d_in[2];
  const float* Wk = (const float*)d_in[3];
  const float* Wv = (const float*)d_in[4];
  float* out = (float*)d_out;

  // workspace layout (total < 16 MiB):
  char* ws = (char*)d_ws;
  f16* Wtq = (f16*)(ws);                  // 80*768*2  = 122880 B
  f16* Wtk = (f16*)(ws + 122880);         // 80*288*2  =  46080 B
  f16* Wtv = (f16*)(ws + 168960);         // 46080 B  (end 215040)
  f16* Qw  = (f16*)(ws + 262144);         // 32768*80*2 = 5242880 B
  f16* Kw  = (f16*)(ws + 5505024);
  f16* Vw  = (f16*)(ws + 10747904);       // end 15990784

  w_prep <<<240, 256, 0, stream>>>(Wq, Wk, Wv, Wtq, Wtk, Wtv);
  proj_q <<<512, 256, 0, stream>>>(x, Wtq, Qw);
  proj_kv<<<512, 256, 0, stream>>>(y, Wtk, Wtv, Kw, Vw);
  attn   <<<512, 256, 0, stream>>>(Qw, Kw, Vw, out);
}